// Round 4
// baseline (98.163 us; speedup 1.0000x reference)
//
#include <hip/hip_runtime.h>

// S6 selective scan: BT=8, L=8192, F=128, N=16
// y[b,t,f] = sum_n h[b,t,f,n]*C[b,t,n],  h = dA*h + dB*x  (diagonal A)
//
// k_pre       : x @ {Wb,Wc,Wd} -> G[token][48] = {dA[16], dB[16], C[16]}
//               4-way K-split, 2 tokens/thread, conflict-free W layout in LDS
// k_local     : per-(b,chunk) local scan (h0=0) -> q[b,c,f,n], P[b,c,n]
//               CH=256 chunks of LC=32 -> 4 waves/SIMD for latency hiding
// k_chunkscan : scan over 256 chunks -> Hin[b,c,f,n] (16-deep reg prefetch)
// k_final     : replay local scan seeded with Hin, write y

#define BTc   8
#define Lseq  8192
#define Fdim  128
#define Ndim  16
#define CH    256          // number of chunks
#define LC    32           // Lseq / CH

// 512 blocks x 256 thr; thread=(t2,ks): tokens block*128+t2 and +64, K-quarter ks
__global__ __launch_bounds__(256) void k_pre(
    const float* __restrict__ x,
    const float* __restrict__ Wb, const float* __restrict__ bb,
    const float* __restrict__ Wc, const float* __restrict__ bc,
    const float* __restrict__ Wd, const float* __restrict__ bd,
    const float* __restrict__ A,  float* __restrict__ G)
{
    // Wl[j][ks][36]: pad 36 puts ks-slices in distinct banks:
    // bank(j,ks,kk) = (16j + 4ks + 4kk)%32 -> 4 distinct banks per (j,kk)
    __shared__ float Wl[33][4][36];   // 19 KB
    const int tid = threadIdx.x;
    for (int idx = tid; idx < 33 * 128; idx += 256) {
        int j = idx >> 7, k = idx & 127;
        float v;
        if (j < 16)      v = Wb[k * 16 + j];
        else if (j < 32) v = Wc[k * 16 + (j - 16)];
        else             v = Wd[k];
        Wl[j][k >> 5][k & 31] = v;
    }
    __syncthreads();

    const int t2 = tid >> 2, ks = tid & 3;
    const size_t tokA = (size_t)blockIdx.x * 128 + t2;   // + t2 in [0,64)
    const float4* xA = reinterpret_cast<const float4*>(x + tokA * 128 + ks * 32);
    const float4* xB = reinterpret_cast<const float4*>(x + (tokA + 64) * 128 + ks * 32);

    float accA[33], accB[33];
#pragma unroll
    for (int j = 0; j < 33; ++j) { accA[j] = 0.f; accB[j] = 0.f; }

#pragma unroll 2
    for (int kk = 0; kk < 8; ++kk) {
        float4 a = xA[kk], b = xB[kk];
#pragma unroll
        for (int j = 0; j < 33; ++j) {
            float4 w = *reinterpret_cast<const float4*>(&Wl[j][ks][kk * 4]);
            accA[j] = fmaf(a.x, w.x, accA[j]);
            accA[j] = fmaf(a.y, w.y, accA[j]);
            accA[j] = fmaf(a.z, w.z, accA[j]);
            accA[j] = fmaf(a.w, w.w, accA[j]);
            accB[j] = fmaf(b.x, w.x, accB[j]);
            accB[j] = fmaf(b.y, w.y, accB[j]);
            accB[j] = fmaf(b.z, w.z, accB[j]);
            accB[j] = fmaf(b.w, w.w, accB[j]);
        }
    }

    // butterfly reduce over ks (lanes quad): every lane ends with full sums
    float sel[33];
#pragma unroll
    for (int j = 0; j < 33; ++j) {
        accA[j] += __shfl_xor(accA[j], 1);
        accA[j] += __shfl_xor(accA[j], 2);
        accB[j] += __shfl_xor(accB[j], 1);
        accB[j] += __shfl_xor(accB[j], 2);
        sel[j] = (ks & 1) ? accB[j] : accA[j];
    }

    if (ks < 2) {                      // lane ks=0 -> token A, ks=1 -> token B
        const size_t tok = tokA + (size_t)(ks & 1) * 64;
        float v = sel[32] + bd[0];
        float delta = fmaxf(v, 0.f) + log1pf(expf(-fabsf(v)));
        float out[48];
#pragma unroll
        for (int n = 0; n < 16; ++n) {
            float An = A[n];
            float dA = expf(delta * An);
            float dB = (dA - 1.f) / An * (sel[n] + bb[n]);
            out[n]      = dA;
            out[16 + n] = dB;
            out[32 + n] = sel[16 + n] + bc[n];
        }
        float4* Gr = reinterpret_cast<float4*>(G + tok * 48);
#pragma unroll
        for (int p = 0; p < 12; ++p)
            Gr[p] = make_float4(out[4*p], out[4*p+1], out[4*p+2], out[4*p+3]);
    }
}

__global__ __launch_bounds__(128, 4) void k_local(
    const float* __restrict__ x, const float* __restrict__ G,
    float* __restrict__ q, float* __restrict__ P)
{
    const int c = blockIdx.x, b = blockIdx.y;
    const int f = threadIdx.x;
    const size_t tok0 = (size_t)b * Lseq + (size_t)c * LC;
    const float4* Gp = reinterpret_cast<const float4*>(G + tok0 * 48);
    const float* xp = x + tok0 * Fdim + f;

    float h[16], pr[16];
#pragma unroll
    for (int n = 0; n < 16; ++n) { h[n] = 0.f; pr[n] = 1.f; }

#pragma unroll 2
    for (int t = 0; t < LC; ++t) {
        float4 g[8];                      // dA[16], dB[16] — uniform address
#pragma unroll
        for (int p = 0; p < 8; ++p) g[p] = Gp[t * 12 + p];
        float xv = xp[t * Fdim];
        const float* dA = reinterpret_cast<const float*>(&g[0]);
        const float* dB = reinterpret_cast<const float*>(&g[4]);
#pragma unroll
        for (int n = 0; n < 16; ++n) {
            h[n]  = fmaf(dA[n], h[n], dB[n] * xv);
            pr[n] *= dA[n];
        }
    }

    float4* qp = reinterpret_cast<float4*>(q + ((size_t)(b * CH + c) * 128 + f) * 16);
#pragma unroll
    for (int n4 = 0; n4 < 4; ++n4)
        qp[n4] = make_float4(h[4*n4], h[4*n4+1], h[4*n4+2], h[4*n4+3]);
    if (f == 0) {
        float4* Pp = reinterpret_cast<float4*>(P + (size_t)(b * CH + c) * 16);
#pragma unroll
        for (int n4 = 0; n4 < 4; ++n4)
            Pp[n4] = make_float4(pr[4*n4], pr[4*n4+1], pr[4*n4+2], pr[4*n4+3]);
    }
}

__global__ __launch_bounds__(256) void k_chunkscan(
    const float* __restrict__ q, const float* __restrict__ P,
    float* __restrict__ Hin)
{
    int id = blockIdx.x * 256 + threadIdx.x;   // 16384 = 8*128*16
    int b  = id >> 11;
    int fn = id & 2047;
    int n  = id & 15;
    float H = 0.f;
    size_t qb = (size_t)b * CH * 2048 + fn;
    size_t pb = (size_t)b * CH * 16 + n;
    for (int cg = 0; cg < CH; cg += 16) {
        float Pr[16], qr[16];
#pragma unroll
        for (int i = 0; i < 16; ++i) {
            Pr[i] = P[pb + (size_t)(cg + i) * 16];
            qr[i] = q[qb + (size_t)(cg + i) * 2048];
        }
#pragma unroll
        for (int i = 0; i < 16; ++i) {
            Hin[qb + (size_t)(cg + i) * 2048] = H;
            H = fmaf(Pr[i], H, qr[i]);
        }
    }
}

__global__ __launch_bounds__(128, 4) void k_final(
    const float* __restrict__ x, const float* __restrict__ G,
    const float* __restrict__ Hin, float* __restrict__ y)
{
    const int c = blockIdx.x, b = blockIdx.y;
    const int f = threadIdx.x;
    const size_t tok0 = (size_t)b * Lseq + (size_t)c * LC;
    const float4* Gp = reinterpret_cast<const float4*>(G + tok0 * 48);
    const float* xp = x + tok0 * Fdim + f;
    float*       yp = y + tok0 * Fdim + f;

    float h[16];
    const float4* hp = reinterpret_cast<const float4*>(Hin + ((size_t)(b * CH + c) * 128 + f) * 16);
#pragma unroll
    for (int n4 = 0; n4 < 4; ++n4) {
        float4 v = hp[n4];
        h[4*n4] = v.x; h[4*n4+1] = v.y; h[4*n4+2] = v.z; h[4*n4+3] = v.w;
    }

#pragma unroll 2
    for (int t = 0; t < LC; ++t) {
        float4 g[12];                     // dA | dB | C — uniform address
#pragma unroll
        for (int p = 0; p < 12; ++p) g[p] = Gp[t * 12 + p];
        float xv = xp[t * Fdim];
        const float* dA = reinterpret_cast<const float*>(&g[0]);
        const float* dB = reinterpret_cast<const float*>(&g[4]);
        const float* Cc = reinterpret_cast<const float*>(&g[8]);
        float yacc = 0.f;
#pragma unroll
        for (int n = 0; n < 16; ++n) {
            h[n] = fmaf(dA[n], h[n], dB[n] * xv);
            yacc = fmaf(Cc[n], h[n], yacc);
        }
        yp[t * Fdim] = yacc;
    }
}

extern "C" void kernel_launch(void* const* d_in, const int* in_sizes, int n_in,
                              void* d_out, int out_size, void* d_ws, size_t ws_size,
                              hipStream_t stream) {
    const float* x  = (const float*)d_in[0];
    const float* Wb = (const float*)d_in[1];
    const float* bb = (const float*)d_in[2];
    const float* Wc = (const float*)d_in[3];
    const float* bc = (const float*)d_in[4];
    const float* Wd = (const float*)d_in[5];
    const float* bd = (const float*)d_in[6];
    const float* A  = (const float*)d_in[7];
    float* y = (float*)d_out;

    float* G   = (float*)d_ws;                           // 65536*48   = 12.6 MB
    float* q   = G   + (size_t)BTc * Lseq * 48;          // 8*256*2048 = 16.8 MB
    float* P   = q   + (size_t)BTc * CH * Fdim * Ndim;   // 8*256*16   = 128 KB
    float* Hin = P   + (size_t)BTc * CH * Ndim;          // 8*256*2048 = 16.8 MB

    k_pre<<<dim3(512), 256, 0, stream>>>(x, Wb, bb, Wc, bc, Wd, bd, A, G);
    k_local<<<dim3(CH, BTc), 128, 0, stream>>>(x, G, q, P);
    k_chunkscan<<<dim3(BTc * Fdim * Ndim / 256), 256, 0, stream>>>(q, P, Hin);
    k_final<<<dim3(CH, BTc), 128, 0, stream>>>(x, G, Hin, y);
}

// Round 5
// 80.431 us; speedup vs baseline: 1.2205x; 1.2205x over previous
//
#include <hip/hip_runtime.h>

// S6 selective scan: BT=8, L=8192, F=128, N=16
// y[b,t,f] = sum_n h[b,t,f,n]*C[b,t,n],  h = dA*h + dB*x  (diagonal A)
//
// k_pre       : x @ {Wb,Wc,Wd} -> G[token][48] = {dA[16],dB[16],C[16]}
//               + per-chunk delta-sum S[b*CH+c] (P = exp(A*S) later)
// k_local     : per-(b,chunk) local scan (h0=0) -> q[b,c,f,n]
//               G staged in LDS, per-token ds_read_b128 broadcasts
// k_chunkscan : scan over chunks -> Hin[b,c,f,n]; P recomputed as exp(A*S)
// k_final     : replay local scan seeded with Hin, write y

#define BTc   8
#define Lseq  8192
#define Fdim  128
#define Ndim  16
#define CH    128          // number of chunks
#define LC    64           // Lseq / CH

// 512 blocks x 256 thr; thread=(t2,ks): tokens blk*128+t2 and +64, K-quarter ks
__global__ __launch_bounds__(256) void k_pre(
    const float* __restrict__ x,
    const float* __restrict__ Wb, const float* __restrict__ bb,
    const float* __restrict__ Wc, const float* __restrict__ bc,
    const float* __restrict__ Wd, const float* __restrict__ bd,
    const float* __restrict__ A,  float* __restrict__ G,
    float* __restrict__ S)
{
    // Wl[j][ks][36]: pad 36 puts ks-slices in distinct banks
    __shared__ float Wl[33][4][36];   // 19 KB
    __shared__ float Dl[2][64];       // per-token delta, for chunk sums
    const int tid = threadIdx.x;
    for (int idx = tid; idx < 33 * 128; idx += 256) {
        int j = idx >> 7, k = idx & 127;
        float v;
        if (j < 16)      v = Wb[k * 16 + j];
        else if (j < 32) v = Wc[k * 16 + (j - 16)];
        else             v = Wd[k];
        Wl[j][k >> 5][k & 31] = v;
    }
    __syncthreads();

    const int t2 = tid >> 2, ks = tid & 3;
    const size_t tokA = (size_t)blockIdx.x * 128 + t2;
    const float4* xA = reinterpret_cast<const float4*>(x + tokA * 128 + ks * 32);
    const float4* xB = reinterpret_cast<const float4*>(x + (tokA + 64) * 128 + ks * 32);

    float accA[33], accB[33];
#pragma unroll
    for (int j = 0; j < 33; ++j) { accA[j] = 0.f; accB[j] = 0.f; }

#pragma unroll 2
    for (int kk = 0; kk < 8; ++kk) {
        float4 a = xA[kk], b = xB[kk];
#pragma unroll
        for (int j = 0; j < 33; ++j) {
            float4 w = *reinterpret_cast<const float4*>(&Wl[j][ks][kk * 4]);
            accA[j] = fmaf(a.x, w.x, accA[j]);
            accA[j] = fmaf(a.y, w.y, accA[j]);
            accA[j] = fmaf(a.z, w.z, accA[j]);
            accA[j] = fmaf(a.w, w.w, accA[j]);
            accB[j] = fmaf(b.x, w.x, accB[j]);
            accB[j] = fmaf(b.y, w.y, accB[j]);
            accB[j] = fmaf(b.z, w.z, accB[j]);
            accB[j] = fmaf(b.w, w.w, accB[j]);
        }
    }

    float sel[33];
#pragma unroll
    for (int j = 0; j < 33; ++j) {
        accA[j] += __shfl_xor(accA[j], 1);
        accA[j] += __shfl_xor(accA[j], 2);
        accB[j] += __shfl_xor(accB[j], 1);
        accB[j] += __shfl_xor(accB[j], 2);
        sel[j] = (ks & 1) ? accB[j] : accA[j];
    }

    if (ks < 2) {                      // ks=0 -> token A, ks=1 -> token B
        const size_t tok = tokA + (size_t)(ks & 1) * 64;
        float v = sel[32] + bd[0];
        float delta = fmaxf(v, 0.f) + log1pf(expf(-fabsf(v)));
        Dl[ks][t2] = delta;
        float out[48];
#pragma unroll
        for (int n = 0; n < 16; ++n) {
            float An = A[n];
            float dA = expf(delta * An);
            float dB = (dA - 1.f) / An * (sel[n] + bb[n]);
            out[n]      = dA;
            out[16 + n] = dB;
            out[32 + n] = sel[16 + n] + bc[n];
        }
        float4* Gr = reinterpret_cast<float4*>(G + tok * 48);
#pragma unroll
        for (int p = 0; p < 12; ++p)
            Gr[p] = make_float4(out[4*p], out[4*p+1], out[4*p+2], out[4*p+3]);
    }
    __syncthreads();

    // chunk delta-sums: block covers exactly 2 chunks (2*blk, 2*blk+1)
    if (tid < 128) {
        float val = Dl[tid >> 6][tid & 63];
#pragma unroll
        for (int m = 1; m < 64; m <<= 1) val += __shfl_xor(val, m);
        if ((tid & 63) == 0) S[blockIdx.x * 2 + (tid >> 6)] = val;
    }
}

__global__ __launch_bounds__(128, 2) void k_local(
    const float* __restrict__ x, const float* __restrict__ G,
    float* __restrict__ q)
{
    __shared__ float Gl[LC][32];      // dA | dB per token, 8 KB
    const int c = blockIdx.x, b = blockIdx.y;
    const int f = threadIdx.x;
    const size_t tok0 = (size_t)b * Lseq + (size_t)c * LC;

    const float4* Gg = reinterpret_cast<const float4*>(G + tok0 * 48);
    float4* Gs = reinterpret_cast<float4*>(&Gl[0][0]);
    for (int idx = f; idx < LC * 8; idx += 128) {
        int t = idx >> 3, p = idx & 7;
        Gs[idx] = Gg[t * 12 + p];
    }
    __syncthreads();

    float h[16];
#pragma unroll
    for (int n = 0; n < 16; ++n) h[n] = 0.f;

    const float* xp = x + tok0 * Fdim + f;
#pragma unroll 2
    for (int t = 0; t < LC; ++t) {
        float xv = xp[t * Fdim];
        const float4* gp4 = reinterpret_cast<const float4*>(&Gl[t][0]);
        float da[16], db[16];
#pragma unroll
        for (int p = 0; p < 4; ++p) {
            float4 va = gp4[p], vb = gp4[4 + p];
            da[4*p] = va.x; da[4*p+1] = va.y; da[4*p+2] = va.z; da[4*p+3] = va.w;
            db[4*p] = vb.x; db[4*p+1] = vb.y; db[4*p+2] = vb.z; db[4*p+3] = vb.w;
        }
#pragma unroll
        for (int n = 0; n < 16; ++n)
            h[n] = fmaf(da[n], h[n], db[n] * xv);
    }

    float4* qp = reinterpret_cast<float4*>(q + ((size_t)(b * CH + c) * 128 + f) * 16);
#pragma unroll
    for (int n4 = 0; n4 < 4; ++n4)
        qp[n4] = make_float4(h[4*n4], h[4*n4+1], h[4*n4+2], h[4*n4+3]);
}

__global__ __launch_bounds__(256) void k_chunkscan(
    const float* __restrict__ q, const float* __restrict__ S,
    const float* __restrict__ A, float* __restrict__ Hin)
{
    int id = blockIdx.x * 256 + threadIdx.x;   // 16384 = 8*128*16
    int b  = id >> 11;
    int fn = id & 2047;
    int n  = id & 15;
    float An = A[n];
    float H = 0.f;
    size_t qb = (size_t)b * CH * 2048 + fn;
    const float* Sb = S + b * CH;
    for (int cg = 0; cg < CH; cg += 16) {
        float Sr[16], qr[16];
#pragma unroll
        for (int i = 0; i < 16; ++i) {
            Sr[i] = Sb[cg + i];
            qr[i] = q[qb + (size_t)(cg + i) * 2048];
        }
#pragma unroll
        for (int i = 0; i < 16; ++i) {
            Hin[qb + (size_t)(cg + i) * 2048] = H;
            H = fmaf(__expf(An * Sr[i]), H, qr[i]);
        }
    }
}

__global__ __launch_bounds__(128, 2) void k_final(
    const float* __restrict__ x, const float* __restrict__ G,
    const float* __restrict__ Hin, float* __restrict__ y)
{
    __shared__ float Gl[LC][48];      // dA | dB | C per token, 12 KB
    const int c = blockIdx.x, b = blockIdx.y;
    const int f = threadIdx.x;
    const size_t tok0 = (size_t)b * Lseq + (size_t)c * LC;

    const float4* Gg = reinterpret_cast<const float4*>(G + tok0 * 48);
    float4* Gs = reinterpret_cast<float4*>(&Gl[0][0]);
    for (int idx = f; idx < LC * 12; idx += 128)
        Gs[idx] = Gg[idx];
    __syncthreads();

    float h[16];
    const float4* hp = reinterpret_cast<const float4*>(Hin + ((size_t)(b * CH + c) * 128 + f) * 16);
#pragma unroll
    for (int n4 = 0; n4 < 4; ++n4) {
        float4 v = hp[n4];
        h[4*n4] = v.x; h[4*n4+1] = v.y; h[4*n4+2] = v.z; h[4*n4+3] = v.w;
    }

    const float* xp = x + tok0 * Fdim + f;
    float*       yp = y + tok0 * Fdim + f;
#pragma unroll 2
    for (int t = 0; t < LC; ++t) {
        float xv = xp[t * Fdim];
        const float4* gp4 = reinterpret_cast<const float4*>(&Gl[t][0]);
        float da[16], db[16], cc[16];
#pragma unroll
        for (int p = 0; p < 4; ++p) {
            float4 va = gp4[p], vb = gp4[4 + p], vc = gp4[8 + p];
            da[4*p] = va.x; da[4*p+1] = va.y; da[4*p+2] = va.z; da[4*p+3] = va.w;
            db[4*p] = vb.x; db[4*p+1] = vb.y; db[4*p+2] = vb.z; db[4*p+3] = vb.w;
            cc[4*p] = vc.x; cc[4*p+1] = vc.y; cc[4*p+2] = vc.z; cc[4*p+3] = vc.w;
        }
        float yacc = 0.f;
#pragma unroll
        for (int n = 0; n < 16; ++n) {
            h[n] = fmaf(da[n], h[n], db[n] * xv);
            yacc = fmaf(cc[n], h[n], yacc);
        }
        yp[t * Fdim] = yacc;
    }
}

extern "C" void kernel_launch(void* const* d_in, const int* in_sizes, int n_in,
                              void* d_out, int out_size, void* d_ws, size_t ws_size,
                              hipStream_t stream) {
    const float* x  = (const float*)d_in[0];
    const float* Wb = (const float*)d_in[1];
    const float* bb = (const float*)d_in[2];
    const float* Wc = (const float*)d_in[3];
    const float* bc = (const float*)d_in[4];
    const float* Wd = (const float*)d_in[5];
    const float* bd = (const float*)d_in[6];
    const float* A  = (const float*)d_in[7];
    float* y = (float*)d_out;

    float* G   = (float*)d_ws;                           // 65536*48   = 12.6 MB
    float* q   = G   + (size_t)BTc * Lseq * 48;          // 8*128*2048 = 8.4 MB
    float* Hin = q   + (size_t)BTc * CH * Fdim * Ndim;   // 8*128*2048 = 8.4 MB
    float* S   = Hin + (size_t)BTc * CH * Fdim * Ndim;   // 1024 floats

    k_pre<<<dim3(512), 256, 0, stream>>>(x, Wb, bb, Wc, bc, Wd, bd, A, G, S);
    k_local<<<dim3(CH, BTc), 128, 0, stream>>>(x, G, q);
    k_chunkscan<<<dim3(BTc * Fdim * Ndim / 256), 256, 0, stream>>>(q, S, A, Hin);
    k_final<<<dim3(CH, BTc), 128, 0, stream>>>(x, G, Hin, y);
}